// Round 1
// baseline (643.728 us; speedup 1.0000x reference)
//
#include <hip/hip_runtime.h>
#include <hip/hip_bf16.h>

typedef __attribute__((ext_vector_type(8))) short bf16x8;
typedef __attribute__((ext_vector_type(4))) float f32x4;
typedef __attribute__((ext_vector_type(8))) short shortx8;

// Workspace layout (bytes)
#define WBT_OFF_B 71368704ull   // after xsp: 16*66*66*512*2
#define S_OFF_B   76087296ull   // after wbT: 9*512*512*2
#define D_OFF_B   76120064ull
#define W2_OFF_B  76152832ull
// total ~77.2 MB

__device__ __forceinline__ void gload16(const void* g, void* l) {
  __builtin_amdgcn_global_load_lds((const __attribute__((address_space(1))) void*)g,
                                   (__attribute__((address_space(3))) void*)l, 16, 0, 0);
}

// s[n][c] = (dl[n] @ style_w)*1/sqrt(512) + style_b
__global__ void style_kernel(const float* __restrict__ dlat, const float* __restrict__ sw,
                             const float* __restrict__ sb, const int* __restrict__ lidx,
                             float* __restrict__ s) {
  int gid = blockIdx.x * 256 + threadIdx.x;         // 16*512
  int n = gid >> 9, c = gid & 511;
  const float* dl = dlat + (n * 14 + lidx[0]) * 512;
  float acc = 0.f;
  for (int k = 0; k < 512; ++k) acc = fmaf(dl[k], sw[k * 512 + c], acc);
  s[gid] = acc * 0.044194173824159216f + sb[c];
}

// W2[i][o] = sum_taps weight[t][i][o]^2
__global__ void w2_kernel(const float* __restrict__ weight, float* __restrict__ w2) {
  int gid = blockIdx.x * 256 + threadIdx.x;         // 512*512
  int i = gid >> 9, o = gid & 511;
  float acc = 0.f;
#pragma unroll
  for (int t = 0; t < 9; ++t) { float v = weight[(t * 512 + i) * 512 + o]; acc = fmaf(v, v, acc); }
  w2[gid] = acc;
}

// d[n][o] = rsqrt( (1/4608) * sum_i W2[i][o]*s[n][i]^2 + 1e-8 )
__global__ void d_kernel(const float* __restrict__ w2, const float* __restrict__ s,
                         float* __restrict__ dd) {
  int gid = blockIdx.x * 256 + threadIdx.x;         // 16*512
  int n = gid >> 9, o = gid & 511;
  const float* sn = s + (n << 9);
  float acc = 0.f;
  for (int i = 0; i < 512; ++i) { float sv = sn[i]; acc = fmaf(w2[(i << 9) + o], sv * sv, acc); }
  dd[gid] = rsqrtf(acc * (1.0f / 4608.0f) + 1e-8f);
}

// wbT[t][o][i] = bf16(weight[t][i][o] / sqrt(4608))
__global__ void wbt_kernel(const float* __restrict__ weight, __hip_bfloat16* __restrict__ wbT) {
  int gid = blockIdx.x * 256 + threadIdx.x;         // 9*512*512
  int i = gid & 511, o = (gid >> 9) & 511, t = gid >> 18;
  float v = weight[(t * 512 + i) * 512 + o] * 0.014731391274719739f;
  wbT[gid] = __float2bfloat16(v);
}

// xsp[n][hp][wp][c] = bf16(x[n][hp-1][wp-1][c] * s[n][c]), zero-padded border
__global__ void xpad_kernel(const float* __restrict__ x, const float* __restrict__ s,
                            __hip_bfloat16* __restrict__ xsp) {
  int gid = blockIdx.x * 256 + threadIdx.x;         // 16*66*66*64
  int c8 = gid & 63;
  int pos = gid >> 6;
  int wp = pos % 66; int t1 = pos / 66; int hp = t1 % 66; int n = t1 / 66;
  shortx8 ov;
  if ((unsigned)(hp - 1) < 64u && (unsigned)(wp - 1) < 64u) {
    const float* xp = &x[((((n << 6) + (hp - 1)) << 6) + (wp - 1)) * 512 + (c8 << 3)];
    const float* sp = &s[(n << 9) + (c8 << 3)];
    float4 a0 = *(const float4*)xp, a1 = *(const float4*)(xp + 4);
    float4 s0 = *(const float4*)sp, s1 = *(const float4*)(sp + 4);
    float r[8] = {a0.x * s0.x, a0.y * s0.y, a0.z * s0.z, a0.w * s0.w,
                  a1.x * s1.x, a1.y * s1.y, a1.z * s1.z, a1.w * s1.w};
#pragma unroll
    for (int j = 0; j < 8; ++j) { __hip_bfloat16 h = __float2bfloat16(r[j]); ov[j] = *(short*)&h; }
  } else {
#pragma unroll
    for (int j = 0; j < 8; ++j) ov[j] = 0;
  }
  *(shortx8*)&xsp[(size_t)pos * 512 + (c8 << 3)] = ov;
}

// Implicit-GEMM conv: M=65536 (n,h,w), N=512 (o), K=9 taps x 512.
// 128x128 tile, BK=32, 4 waves (2x2), mfma 16x16x32 bf16, fused epilogue.
__global__ void conv_kernel(const __hip_bfloat16* __restrict__ xsp,
                            const __hip_bfloat16* __restrict__ wbT,
                            const float* __restrict__ dbuf,
                            const float* __restrict__ bias,
                            const float* __restrict__ noise,
                            const float* __restrict__ nstr,
                            float* __restrict__ out) {
  __shared__ short Ald[128 * 32];
  __shared__ short Bld[128 * 32];

  int bid = blockIdx.x;
  bid = (bid & 7) * 256 + (bid >> 3);               // XCD-contiguous chunks (2048 % 8 == 0)
  int mTile = bid >> 2, nTile = bid & 3;

  int tid = threadIdx.x;
  int lane = tid & 63, wv = tid >> 6;
  int wm = wv >> 1, wn = wv & 1;

  int m_base = mTile << 7;
  int n_img = m_base >> 12;                         // 4096 positions per image
  int h_b = (m_base & 4095) >> 6;
  int oB = nTile << 7;

  // staging: chunk q covers 16 rows; wave wv owns q=wv and q=4+wv (both tiles)
  int rlow = (wv << 4) + (lane >> 2);               // row within [0,64)
  int seg = (lane & 3) << 3;                        // bf16 element offset 0/8/16/24

  int xb0 = ((n_img * 66 + h_b) * 66 + rlow) * 512 + seg;        // rows 0..63 (tr>>6 = 0)
  int xb1 = ((n_img * 66 + h_b + 1) * 66 + rlow) * 512 + seg;    // rows 64..127
  int bb0 = (oB + rlow) * 512 + seg;
  int bb1 = (oB + 64 + rlow) * 512 + seg;

  short* la0 = &Ald[wv * 512];
  short* la1 = &Ald[(4 + wv) * 512];
  short* lb0 = &Bld[wv * 512];
  short* lb1 = &Bld[(4 + wv) * 512];

  int arow = (wm << 6) + (lane & 15);
  int brow = (wn << 6) + (lane & 15);
  int koff = (lane >> 4) << 3;

  f32x4 acc[4][4];
#pragma unroll
  for (int f = 0; f < 4; ++f)
#pragma unroll
    for (int g = 0; g < 4; ++g) acc[f][g] = {0.f, 0.f, 0.f, 0.f};

#pragma unroll 1
  for (int tap = 0; tap < 9; ++tap) {
    int toff = ((tap / 3) * 66 + (tap % 3)) * 512;
    const __hip_bfloat16* ga0 = xsp + xb0 + toff;
    const __hip_bfloat16* ga1 = xsp + xb1 + toff;
    const __hip_bfloat16* gb0 = wbT + tap * 262144 + bb0;
    const __hip_bfloat16* gb1 = wbT + tap * 262144 + bb1;
#pragma unroll 1
    for (int kb = 0; kb < 16; ++kb) {
      __syncthreads();                              // previous tile consumed
      gload16(ga0, la0); gload16(ga1, la1);
      gload16(gb0, lb0); gload16(gb1, lb1);
      __syncthreads();                              // vmcnt(0) drained by compiler
      ga0 += 32; ga1 += 32; gb0 += 32; gb1 += 32;
      bf16x8 af[4], bfr[4];
#pragma unroll
      for (int f = 0; f < 4; ++f) af[f] = *(const bf16x8*)&Ald[(arow + (f << 4)) * 32 + koff];
#pragma unroll
      for (int g = 0; g < 4; ++g) bfr[g] = *(const bf16x8*)&Bld[(brow + (g << 4)) * 32 + koff];
#pragma unroll
      for (int f = 0; f < 4; ++f)
#pragma unroll
        for (int g = 0; g < 4; ++g)
          acc[f][g] = __builtin_amdgcn_mfma_f32_16x16x32_bf16(af[f], bfr[g], acc[f][g], 0, 0, 0);
    }
  }

  // epilogue: y*d + noise*ns + bias -> leaky_relu*sqrt(2)
  float ns = nstr[0];
  int ocol = oB + (wn << 6) + (lane & 15);
  float dv[4], bv[4];
#pragma unroll
  for (int g = 0; g < 4; ++g) {
    dv[g] = dbuf[(n_img << 9) + ocol + (g << 4)];
    bv[g] = bias[ocol + (g << 4)];
  }
  int mrow0 = m_base + (wm << 6) + ((lane >> 4) << 2);
#pragma unroll
  for (int f = 0; f < 4; ++f) {
#pragma unroll
    for (int j = 0; j < 4; ++j) {
      int m = mrow0 + (f << 4) + j;
      float nz = noise[m] * ns;
      float* op = out + (size_t)m * 512 + ocol;
#pragma unroll
      for (int g = 0; g < 4; ++g) {
        float v = fmaf(acc[f][g][j], dv[g], nz + bv[g]);
        v = (v > 0.f ? v : 0.2f * v) * 1.4142135623730951f;
        op[g << 4] = v;
      }
    }
  }
}

extern "C" void kernel_launch(void* const* d_in, const int* in_sizes, int n_in,
                              void* d_out, int out_size, void* d_ws, size_t ws_size,
                              hipStream_t stream) {
  const float* x     = (const float*)d_in[0];
  const float* dlat  = (const float*)d_in[1];
  const float* sw    = (const float*)d_in[2];
  const float* sb    = (const float*)d_in[3];
  const float* wt    = (const float*)d_in[4];
  const float* bias  = (const float*)d_in[5];
  const float* nstr  = (const float*)d_in[6];
  const float* noise = (const float*)d_in[7];
  const int*   lidx  = (const int*)d_in[8];
  float* out = (float*)d_out;

  char* ws = (char*)d_ws;
  __hip_bfloat16* xsp = (__hip_bfloat16*)ws;
  __hip_bfloat16* wbT = (__hip_bfloat16*)(ws + WBT_OFF_B);
  float* sbuf = (float*)(ws + S_OFF_B);
  float* dbuf = (float*)(ws + D_OFF_B);
  float* w2   = (float*)(ws + W2_OFF_B);

  style_kernel<<<32, 256, 0, stream>>>(dlat, sw, sb, lidx, sbuf);
  w2_kernel<<<1024, 256, 0, stream>>>(wt, w2);
  d_kernel<<<32, 256, 0, stream>>>(w2, sbuf, dbuf);
  wbt_kernel<<<9216, 256, 0, stream>>>(wt, wbT);
  xpad_kernel<<<17424, 256, 0, stream>>>(x, sbuf, xsp);
  conv_kernel<<<2048, 256, 0, stream>>>(xsp, wbT, dbuf, bias, noise, nstr, out);
}

// Round 2
// 641.218 us; speedup vs baseline: 1.0039x; 1.0039x over previous
//
#include <hip/hip_runtime.h>
#include <hip/hip_bf16.h>

typedef __attribute__((ext_vector_type(8))) short bf16x8;
typedef __attribute__((ext_vector_type(4))) float f32x4;
typedef __attribute__((ext_vector_type(8))) short shortx8;

// Workspace layout (bytes)
#define WBT_OFF_B 71368704ull   // after xsp: 16*66*66*512*2
#define S_OFF_B   76087296ull   // after wbT: 9*512*512*2
#define D_OFF_B   76120064ull   // dpre: 16*512 f32 partial sums
#define W2_OFF_B  76152832ull
// total ~77.2 MB

__device__ __forceinline__ void gload16(const void* g, void* l) {
  __builtin_amdgcn_global_load_lds((const __attribute__((address_space(1))) void*)g,
                                   (__attribute__((address_space(3))) void*)l, 16, 0, 0);
}

// s[n][c] = (dl[n] @ style_w)*1/sqrt(512) + style_b
__global__ void style_kernel(const float* __restrict__ dlat, const float* __restrict__ sw,
                             const float* __restrict__ sb, const int* __restrict__ lidx,
                             float* __restrict__ s) {
  int gid = blockIdx.x * 256 + threadIdx.x;         // 16*512
  int n = gid >> 9, c = gid & 511;
  const float* dl = dlat + (n * 14 + lidx[0]) * 512;
  float acc = 0.f;
#pragma unroll 4
  for (int k = 0; k < 512; ++k) acc = fmaf(dl[k], sw[k * 512 + c], acc);
  s[gid] = acc * 0.044194173824159216f + sb[c];
}

// W2[i][o] = sum_taps weight[t][i][o]^2
__global__ void w2_kernel(const float* __restrict__ weight, float* __restrict__ w2) {
  int gid = blockIdx.x * 256 + threadIdx.x;         // 512*512
  int i = gid >> 9, o = gid & 511;
  float acc = 0.f;
#pragma unroll
  for (int t = 0; t < 9; ++t) { float v = weight[(t * 512 + i) * 512 + o]; acc = fmaf(v, v, acc); }
  w2[gid] = acc;
}

// dpre[n][o] += sum_{i in chunk} W2[i][o]*s[n][i]^2   (128 blocks: 16n x 4ic x 2oh)
__global__ void dpart_kernel(const float* __restrict__ w2, const float* __restrict__ s,
                             float* __restrict__ dpre) {
  int b = blockIdx.x;
  int n = b >> 3, ic = (b >> 1) & 3, oh = b & 1;
  int o = (oh << 8) + threadIdx.x;
  const float* sn = s + (n << 9) + (ic << 7);
  const float* w2p = w2 + ((ic << 7) << 9) + o;
  float acc = 0.f;
#pragma unroll 4
  for (int i = 0; i < 128; ++i) { float sv = sn[i]; acc = fmaf(w2p[i << 9], sv * sv, acc); }
  atomicAdd(&dpre[(n << 9) + o], acc);
}

// wbT[t][o][i] = bf16(weight[t][i][o] / sqrt(4608)) — LDS tile transpose
__global__ void wbt_kernel(const float* __restrict__ weight, __hip_bfloat16* __restrict__ wbT) {
  __shared__ float tile[64][65];
  int b = blockIdx.x;                                // 9 * 64 (8x8 tiles of 64x64)
  int t = b >> 6; int rem = b & 63;
  int i0 = (rem >> 3) << 6, o0 = (rem & 7) << 6;
  int tr = threadIdx.x >> 4;                         // 0..15
  int tc = (threadIdx.x & 15) << 2;                  // 0,4,..,60
#pragma unroll
  for (int rr = 0; rr < 4; ++rr) {
    int il = tr + (rr << 4);
    float4 v = *(const float4*)&weight[((size_t)(t * 512 + i0 + il) << 9) + o0 + tc];
    tile[il][tc] = v.x; tile[il][tc + 1] = v.y; tile[il][tc + 2] = v.z; tile[il][tc + 3] = v.w;
  }
  __syncthreads();
#pragma unroll
  for (int rr = 0; rr < 4; ++rr) {
    int ol = tr + (rr << 4);
    short4 ov;
#pragma unroll
    for (int j = 0; j < 4; ++j) {
      __hip_bfloat16 h = __float2bfloat16(tile[tc + j][ol] * 0.014731391274719739f);
      ((short*)&ov)[j] = *(short*)&h;
    }
    *(short4*)&wbT[((size_t)(t * 512 + o0 + ol) << 9) + i0 + tc] = ov;
  }
}

// xsp[n][hp][wp][c] = bf16(x[n][hp-1][wp-1][c] * s[n][c]), zero-padded border
__global__ void xpad_kernel(const float* __restrict__ x, const float* __restrict__ s,
                            __hip_bfloat16* __restrict__ xsp) {
  int gid = blockIdx.x * 256 + threadIdx.x;         // 16*66*66*64
  int c8 = gid & 63;
  int pos = gid >> 6;
  int wp = pos % 66; int t1 = pos / 66; int hp = t1 % 66; int n = t1 / 66;
  shortx8 ov;
  if ((unsigned)(hp - 1) < 64u && (unsigned)(wp - 1) < 64u) {
    const float* xp = &x[((((n << 6) + (hp - 1)) << 6) + (wp - 1)) * 512 + (c8 << 3)];
    const float* sp = &s[(n << 9) + (c8 << 3)];
    float4 a0 = *(const float4*)xp, a1 = *(const float4*)(xp + 4);
    float4 s0 = *(const float4*)sp, s1 = *(const float4*)(sp + 4);
    float r[8] = {a0.x * s0.x, a0.y * s0.y, a0.z * s0.z, a0.w * s0.w,
                  a1.x * s1.x, a1.y * s1.y, a1.z * s1.z, a1.w * s1.w};
#pragma unroll
    for (int j = 0; j < 8; ++j) { __hip_bfloat16 h = __float2bfloat16(r[j]); ov[j] = *(short*)&h; }
  } else {
#pragma unroll
    for (int j = 0; j < 8; ++j) ov[j] = 0;
  }
  *(shortx8*)&xsp[(size_t)pos * 512 + (c8 << 3)] = ov;
}

// Implicit-GEMM conv: M=65536 (n,h,w), N=512 (o), K=9 taps x 512.
// 128x128 tile, BK=32, 4 waves (2x2), mfma 16x16x32 bf16, fused epilogue.
__global__ void conv_kernel(const __hip_bfloat16* __restrict__ xsp,
                            const __hip_bfloat16* __restrict__ wbT,
                            const float* __restrict__ dpre,
                            const float* __restrict__ bias,
                            const float* __restrict__ noise,
                            const float* __restrict__ nstr,
                            float* __restrict__ out) {
  __shared__ short Ald[128 * 32];
  __shared__ short Bld[128 * 32];

  int bid = blockIdx.x;
  bid = (bid & 7) * 256 + (bid >> 3);               // XCD-contiguous chunks (2048 % 8 == 0)
  int mTile = bid >> 2, nTile = bid & 3;

  int tid = threadIdx.x;
  int lane = tid & 63, wv = tid >> 6;
  int wm = wv >> 1, wn = wv & 1;

  int m_base = mTile << 7;
  int n_img = m_base >> 12;                         // 4096 positions per image
  int h_b = (m_base & 4095) >> 6;
  int oB = nTile << 7;

  int rlow = (wv << 4) + (lane >> 2);               // row within [0,64)
  int seg = (lane & 3) << 3;                        // bf16 element offset 0/8/16/24

  int xb0 = ((n_img * 66 + h_b) * 66 + rlow) * 512 + seg;        // rows 0..63
  int xb1 = ((n_img * 66 + h_b + 1) * 66 + rlow) * 512 + seg;    // rows 64..127
  int bb0 = (oB + rlow) * 512 + seg;
  int bb1 = (oB + 64 + rlow) * 512 + seg;

  short* la0 = &Ald[wv * 512];
  short* la1 = &Ald[(4 + wv) * 512];
  short* lb0 = &Bld[wv * 512];
  short* lb1 = &Bld[(4 + wv) * 512];

  int arow = (wm << 6) + (lane & 15);
  int brow = (wn << 6) + (lane & 15);
  int koff = (lane >> 4) << 3;

  f32x4 acc[4][4];
#pragma unroll
  for (int f = 0; f < 4; ++f)
#pragma unroll
    for (int g = 0; g < 4; ++g) acc[f][g] = {0.f, 0.f, 0.f, 0.f};

#pragma unroll 1
  for (int tap = 0; tap < 9; ++tap) {
    int toff = ((tap / 3) * 66 + (tap % 3)) * 512;
    const __hip_bfloat16* ga0 = xsp + xb0 + toff;
    const __hip_bfloat16* ga1 = xsp + xb1 + toff;
    const __hip_bfloat16* gb0 = wbT + tap * 262144 + bb0;
    const __hip_bfloat16* gb1 = wbT + tap * 262144 + bb1;
#pragma unroll 1
    for (int kb = 0; kb < 16; ++kb) {
      __syncthreads();                              // previous tile consumed
      gload16(ga0, la0); gload16(ga1, la1);
      gload16(gb0, lb0); gload16(gb1, lb1);
      __syncthreads();                              // vmcnt(0) drained by compiler
      ga0 += 32; ga1 += 32; gb0 += 32; gb1 += 32;
      bf16x8 af[4], bfr[4];
#pragma unroll
      for (int f = 0; f < 4; ++f) af[f] = *(const bf16x8*)&Ald[(arow + (f << 4)) * 32 + koff];
#pragma unroll
      for (int g = 0; g < 4; ++g) bfr[g] = *(const bf16x8*)&Bld[(brow + (g << 4)) * 32 + koff];
#pragma unroll
      for (int f = 0; f < 4; ++f)
#pragma unroll
        for (int g = 0; g < 4; ++g)
          acc[f][g] = __builtin_amdgcn_mfma_f32_16x16x32_bf16(af[f], bfr[g], acc[f][g], 0, 0, 0);
    }
  }

  // epilogue: y*rsqrt(dpre/4608+eps) + noise*ns + bias -> leaky_relu*sqrt(2)
  float ns = nstr[0];
  int ocol = oB + (wn << 6) + (lane & 15);
  float dv[4], bv[4];
#pragma unroll
  for (int g = 0; g < 4; ++g) {
    dv[g] = rsqrtf(dpre[(n_img << 9) + ocol + (g << 4)] * (1.0f / 4608.0f) + 1e-8f);
    bv[g] = bias[ocol + (g << 4)];
  }
  int mrow0 = m_base + (wm << 6) + ((lane >> 4) << 2);
#pragma unroll
  for (int f = 0; f < 4; ++f) {
#pragma unroll
    for (int j = 0; j < 4; ++j) {
      int m = mrow0 + (f << 4) + j;
      float nz = noise[m] * ns;
      float* op = out + (size_t)m * 512 + ocol;
#pragma unroll
      for (int g = 0; g < 4; ++g) {
        float v = fmaf(acc[f][g][j], dv[g], nz + bv[g]);
        v = (v > 0.f ? v : 0.2f * v) * 1.4142135623730951f;
        op[g << 4] = v;
      }
    }
  }
}

extern "C" void kernel_launch(void* const* d_in, const int* in_sizes, int n_in,
                              void* d_out, int out_size, void* d_ws, size_t ws_size,
                              hipStream_t stream) {
  const float* x     = (const float*)d_in[0];
  const float* dlat  = (const float*)d_in[1];
  const float* sw    = (const float*)d_in[2];
  const float* sb    = (const float*)d_in[3];
  const float* wt    = (const float*)d_in[4];
  const float* bias  = (const float*)d_in[5];
  const float* nstr  = (const float*)d_in[6];
  const float* noise = (const float*)d_in[7];
  const int*   lidx  = (const int*)d_in[8];
  float* out = (float*)d_out;

  char* ws = (char*)d_ws;
  __hip_bfloat16* xsp = (__hip_bfloat16*)ws;
  __hip_bfloat16* wbT = (__hip_bfloat16*)(ws + WBT_OFF_B);
  float* sbuf = (float*)(ws + S_OFF_B);
  float* dpre = (float*)(ws + D_OFF_B);
  float* w2   = (float*)(ws + W2_OFF_B);

  hipMemsetAsync(dpre, 0, 16 * 512 * sizeof(float), stream);
  style_kernel<<<32, 256, 0, stream>>>(dlat, sw, sb, lidx, sbuf);
  w2_kernel<<<1024, 256, 0, stream>>>(wt, w2);
  dpart_kernel<<<128, 256, 0, stream>>>(w2, sbuf, dpre);
  wbt_kernel<<<576, 256, 0, stream>>>(wt, wbT);
  xpad_kernel<<<17424, 256, 0, stream>>>(x, sbuf, xsp);
  conv_kernel<<<2048, 256, 0, stream>>>(xsp, wbT, dpre, bias, noise, nstr, out);
}

// Round 4
// 623.718 us; speedup vs baseline: 1.0321x; 1.0281x over previous
//
#include <hip/hip_runtime.h>
#include <hip/hip_bf16.h>

typedef __attribute__((ext_vector_type(8))) short bf16x8;
typedef __attribute__((ext_vector_type(4))) float f32x4;
typedef __attribute__((ext_vector_type(8))) short shortx8;

// Workspace layout (bytes)
#define WBT_OFF_B 71368704ull   // after xsp: 16*66*66*512*2
#define S_OFF_B   76087296ull   // after wbT: 9*512*512*2
#define D_OFF_B   76120064ull   // dpre: 16*512 f32 partial sums
#define W2_OFF_B  76152832ull

__device__ __forceinline__ void gload16(const void* g, void* l) {
  __builtin_amdgcn_global_load_lds((const __attribute__((address_space(1))) void*)g,
                                   (__attribute__((address_space(3))) void*)l, 16, 0, 0);
}

#define BAR() do { __builtin_amdgcn_s_barrier(); __builtin_amdgcn_sched_barrier(0); } while (0)

// ---------------- prep kernels ----------------

__global__ void style_kernel(const float* __restrict__ dlat, const float* __restrict__ sw,
                             const float* __restrict__ sb, const int* __restrict__ lidx,
                             float* __restrict__ s) {
  int gid = blockIdx.x * 256 + threadIdx.x;
  int n = gid >> 9, c = gid & 511;
  const float* dl = dlat + (n * 14 + lidx[0]) * 512;
  float acc = 0.f;
#pragma unroll 4
  for (int k = 0; k < 512; ++k) acc = fmaf(dl[k], sw[k * 512 + c], acc);
  s[gid] = acc * 0.044194173824159216f + sb[c];
}

__global__ void w2_kernel(const float* __restrict__ weight, float* __restrict__ w2) {
  int gid = blockIdx.x * 256 + threadIdx.x;
  int i = gid >> 9, o = gid & 511;
  float acc = 0.f;
#pragma unroll
  for (int t = 0; t < 9; ++t) { float v = weight[(t * 512 + i) * 512 + o]; acc = fmaf(v, v, acc); }
  w2[gid] = acc;
}

__global__ void dpart_kernel(const float* __restrict__ w2, const float* __restrict__ s,
                             float* __restrict__ dpre) {
  int b = blockIdx.x;
  int n = b >> 3, ic = (b >> 1) & 3, oh = b & 1;
  int o = (oh << 8) + threadIdx.x;
  const float* sn = s + (n << 9) + (ic << 7);
  const float* w2p = w2 + ((ic << 7) << 9) + o;
  float acc = 0.f;
#pragma unroll 4
  for (int i = 0; i < 128; ++i) { float sv = sn[i]; acc = fmaf(w2p[i << 9], sv * sv, acc); }
  atomicAdd(&dpre[(n << 9) + o], acc);
}

__global__ void wbt_kernel(const float* __restrict__ weight, __hip_bfloat16* __restrict__ wbT) {
  __shared__ float tile[64][65];
  int b = blockIdx.x;                                // 9 * 64
  int t = b >> 6; int rem = b & 63;
  int i0 = (rem >> 3) << 6, o0 = (rem & 7) << 6;
  int tr = threadIdx.x >> 4;
  int tc = (threadIdx.x & 15) << 2;
#pragma unroll
  for (int rr = 0; rr < 4; ++rr) {
    int il = tr + (rr << 4);
    float4 v = *(const float4*)&weight[((size_t)(t * 512 + i0 + il) << 9) + o0 + tc];
    tile[il][tc] = v.x; tile[il][tc + 1] = v.y; tile[il][tc + 2] = v.z; tile[il][tc + 3] = v.w;
  }
  __syncthreads();
#pragma unroll
  for (int rr = 0; rr < 4; ++rr) {
    int ol = tr + (rr << 4);
    short4 ov;
#pragma unroll
    for (int j = 0; j < 4; ++j) {
      __hip_bfloat16 h = __float2bfloat16(tile[tc + j][ol] * 0.014731391274719739f);
      ((short*)&ov)[j] = *(short*)&h;
    }
    *(short4*)&wbT[((size_t)(t * 512 + o0 + ol) << 9) + i0 + tc] = ov;
  }
}

__global__ void xpad_kernel(const float* __restrict__ x, const float* __restrict__ s,
                            __hip_bfloat16* __restrict__ xsp) {
  int gid = blockIdx.x * 256 + threadIdx.x;
  int c8 = gid & 63;
  int pos = gid >> 6;
  int wp = pos % 66; int t1 = pos / 66; int hp = t1 % 66; int n = t1 / 66;
  shortx8 ov;
  if ((unsigned)(hp - 1) < 64u && (unsigned)(wp - 1) < 64u) {
    const float* xp = &x[((((n << 6) + (hp - 1)) << 6) + (wp - 1)) * 512 + (c8 << 3)];
    const float* sp = &s[(n << 9) + (c8 << 3)];
    float4 a0 = *(const float4*)xp, a1 = *(const float4*)(xp + 4);
    float4 s0 = *(const float4*)sp, s1 = *(const float4*)(sp + 4);
    float r[8] = {a0.x * s0.x, a0.y * s0.y, a0.z * s0.z, a0.w * s0.w,
                  a1.x * s1.x, a1.y * s1.y, a1.z * s1.z, a1.w * s1.w};
#pragma unroll
    for (int j = 0; j < 8; ++j) { __hip_bfloat16 h = __float2bfloat16(r[j]); ov[j] = *(short*)&h; }
  } else {
#pragma unroll
    for (int j = 0; j < 8; ++j) ov[j] = 0;
  }
  *(shortx8*)&xsp[(size_t)pos * 512 + (c8 << 3)] = ov;
}

// ---------------- 4-phase pipelined implicit-GEMM conv ----------------
// BM=256, BN=128, BK=64. 512 threads = 8 waves (4M x 2N), per-wave 64x64.
// 3-deep K-tile pipeline: read buf[t%3], stage tile t+2 into buf[(t+2)%3],
// one half-tile per phase (B, A0, A1), counted vmcnt(6) per K-tile boundary.
// LDS per buf: A 256x64 bf16 (16384 sh) + B 128x64 (8192 sh) = 48KB; x3 = 144KB.
// T2 swizzle: 16B chunk cc of row r stored at cc^(r&7); staging pre-swizzles the
// per-lane GLOBAL source so the gload_lds dest stays linear (rule #21).

__global__ __launch_bounds__(512, 2) void conv_kernel(
    const __hip_bfloat16* __restrict__ xsp,
    const __hip_bfloat16* __restrict__ wbT,
    const float* __restrict__ dpre,
    const float* __restrict__ bias,
    const float* __restrict__ noise,
    const float* __restrict__ nstr,
    float* __restrict__ out) {
  extern __shared__ short lds[];

  int bid = blockIdx.x;
  bid = (bid & 7) * 128 + (bid >> 3);               // XCD swizzle (1024 % 8 == 0)
  int mTile = bid >> 2, nTile = bid & 3;            // mTile-major: 4 nTiles share A panel
  int mBase = mTile << 8;
  int n_img = mBase >> 12;
  int oB = nTile << 7;

  int tid = threadIdx.x, lane = tid & 63, wv = tid >> 6;
  int wm = wv >> 1, wn = wv & 1;

  // ---- staging precompute (per thread: chunk slots tid and tid+512) ----
  int r0 = tid >> 3, r1 = (tid + 512) >> 3;         // rows 0..63 / 64..127 within half
  int cg0 = (tid & 7) ^ (r0 & 7);                   // pre-swizzled global 16B chunk
  int cg1 = (tid & 7) ^ (r1 & 7);

  int m00 = mBase + r0, m01 = mBase + r1;           // A half 0
  int m10 = mBase + 128 + r0, m11 = mBase + 128 + r1;  // A half 1
  int a00 = ((n_img * 66 + ((m00 >> 6) & 63)) * 66 + (m00 & 63)) * 512 + cg0 * 8;
  int a01 = ((n_img * 66 + ((m01 >> 6) & 63)) * 66 + (m01 & 63)) * 512 + cg1 * 8;
  int a10 = ((n_img * 66 + ((m10 >> 6) & 63)) * 66 + (m10 & 63)) * 512 + cg0 * 8;
  int a11 = ((n_img * 66 + ((m11 >> 6) & 63)) * 66 + (m11 & 63)) * 512 + cg1 * 8;
  int b0 = (oB + r0) * 512 + cg0 * 8;
  int b1 = (oB + r1) * 512 + cg1 * 8;

  int dA = wv * 512;                                 // LDS short-offsets (wave-uniform)
  int dB = 16384 + wv * 512;

  auto stageB = [&](int bu, int add) {
    short* base = lds + bu * 24576 + dB;
    gload16(wbT + b0 + add, base);
    gload16(wbT + b1 + add, base + 4096);
  };
  auto stageA0 = [&](int bu, int add) {
    short* base = lds + bu * 24576 + dA;
    gload16(xsp + a00 + add, base);
    gload16(xsp + a01 + add, base + 4096);
  };
  auto stageA1 = [&](int bu, int add) {
    short* base = lds + bu * 24576 + 8192 + dA;
    gload16(xsp + a10 + add, base);
    gload16(xsp + a11 + add, base + 4096);
  };

  // ---- fragment-read helpers (swizzled) ----
  int l15 = lane & 15, l16 = lane >> 4;
  int arowb = wm * 64 + l15;                         // + f*16
  int browb = wn * 64 + l15;                         // + g*16

  f32x4 acc[4][4];
#pragma unroll
  for (int f = 0; f < 4; ++f)
#pragma unroll
    for (int g = 0; g < 4; ++g) acc[f][g] = {0.f, 0.f, 0.f, 0.f};

  // ---- prologue: stage tiles 0,1 (tap 0, kt 0/1) ----
  stageB(0, 0); stageA0(0, 0); stageA1(0, 0);
  stageB(1, 64); stageA0(1, 64); stageA1(1, 64);
  asm volatile("s_waitcnt vmcnt(6)" ::: "memory");   // tile 0 landed
  BAR();

  int cur = 0, sb = 2;
#pragma unroll 1
  for (int t = 0; t < 72; ++t) {
    short* L = lds + cur * 24576;
    int u = t + 2;
    bool doStage = u < 72;
    int tp = u >> 3, kt = u & 7;
    int aAdd = ((tp / 3) * 66 + (tp % 3)) * 512 + kt * 64;
    int bAdd = tp * 262144 + kt * 64;

#define AF(F, KS) (*(const bf16x8*)&L[(arowb + (F)*16) * 64 + ((((KS)*4 + l16) ^ ((arowb + (F)*16) & 7)) << 3)])
#define BFR(G, KS) (*(const bf16x8*)&L[16384 + (browb + (G)*16) * 64 + ((((KS)*4 + l16) ^ ((browb + (G)*16) & 7)) << 3)])
#define PHASE_MFMA(F) \
    acc[F][0] = __builtin_amdgcn_mfma_f32_16x16x32_bf16(a0, b00, acc[F][0], 0, 0, 0); \
    acc[F][0] = __builtin_amdgcn_mfma_f32_16x16x32_bf16(a1, b01, acc[F][0], 0, 0, 0); \
    acc[F][1] = __builtin_amdgcn_mfma_f32_16x16x32_bf16(a0, b10, acc[F][1], 0, 0, 0); \
    acc[F][1] = __builtin_amdgcn_mfma_f32_16x16x32_bf16(a1, b11, acc[F][1], 0, 0, 0); \
    acc[F][2] = __builtin_amdgcn_mfma_f32_16x16x32_bf16(a0, b20, acc[F][2], 0, 0, 0); \
    acc[F][2] = __builtin_amdgcn_mfma_f32_16x16x32_bf16(a1, b21, acc[F][2], 0, 0, 0); \
    acc[F][3] = __builtin_amdgcn_mfma_f32_16x16x32_bf16(a0, b30, acc[F][3], 0, 0, 0); \
    acc[F][3] = __builtin_amdgcn_mfma_f32_16x16x32_bf16(a1, b31, acc[F][3], 0, 0, 0);

    // ---- phase 0: B frags + A row 0; stage B of tile u ----
    bf16x8 b00 = BFR(0, 0), b01 = BFR(0, 1), b10 = BFR(1, 0), b11 = BFR(1, 1);
    bf16x8 b20 = BFR(2, 0), b21 = BFR(2, 1), b30 = BFR(3, 0), b31 = BFR(3, 1);
    bf16x8 a0 = AF(0, 0), a1 = AF(0, 1);
    if (doStage) stageB(sb, bAdd);
    BAR();
    asm volatile("s_waitcnt lgkmcnt(0)" ::: "memory");
    __builtin_amdgcn_sched_barrier(0);
    __builtin_amdgcn_s_setprio(1);
    PHASE_MFMA(0)
    __builtin_amdgcn_s_setprio(0);
    BAR();

    // ---- phase 1: A row 1; stage A0 ----
    a0 = AF(1, 0); a1 = AF(1, 1);
    if (doStage) stageA0(sb, aAdd);
    BAR();
    asm volatile("s_waitcnt lgkmcnt(0)" ::: "memory");
    __builtin_amdgcn_sched_barrier(0);
    __builtin_amdgcn_s_setprio(1);
    PHASE_MFMA(1)
    __builtin_amdgcn_s_setprio(0);
    BAR();

    // ---- phase 2: A row 2; stage A1 ----
    a0 = AF(2, 0); a1 = AF(2, 1);
    if (doStage) stageA1(sb, aAdd);
    BAR();
    asm volatile("s_waitcnt lgkmcnt(0)" ::: "memory");
    __builtin_amdgcn_sched_barrier(0);
    __builtin_amdgcn_s_setprio(1);
    PHASE_MFMA(2)
    __builtin_amdgcn_s_setprio(0);
    BAR();

    // ---- phase 3: A row 3; boundary vmcnt (tile t+1 must be landed) ----
    a0 = AF(3, 0); a1 = AF(3, 1);
    if (t < 70) { asm volatile("s_waitcnt vmcnt(6)" ::: "memory"); }
    else        { asm volatile("s_waitcnt vmcnt(0)" ::: "memory"); }
    BAR();
    asm volatile("s_waitcnt lgkmcnt(0)" ::: "memory");
    __builtin_amdgcn_sched_barrier(0);
    __builtin_amdgcn_s_setprio(1);
    PHASE_MFMA(3)
    __builtin_amdgcn_s_setprio(0);
    BAR();

    cur = (cur == 2) ? 0 : cur + 1;
    sb = (sb == 2) ? 0 : sb + 1;
  }

  // ---- epilogue ----
  float ns = nstr[0];
  int ocol = oB + wn * 64 + l15;
  float dv[4], bv[4];
#pragma unroll
  for (int g = 0; g < 4; ++g) {
    int o = ocol + g * 16;
    dv[g] = rsqrtf(dpre[(n_img << 9) + o] * (1.0f / 4608.0f) + 1e-8f);
    bv[g] = bias[o];
  }
  int mrow0 = mBase + wm * 64 + (l16 << 2);
#pragma unroll
  for (int f = 0; f < 4; ++f) {
#pragma unroll
    for (int j = 0; j < 4; ++j) {
      int m = mrow0 + f * 16 + j;
      float nz = noise[m] * ns;
      float* op = out + (size_t)m * 512 + ocol;
#pragma unroll
      for (int g = 0; g < 4; ++g) {
        float v = fmaf(acc[f][g][j], dv[g], nz + bv[g]);
        v = (v > 0.f ? v : 0.2f * v) * 1.4142135623730951f;
        op[g * 16] = v;
      }
    }
  }
}

extern "C" void kernel_launch(void* const* d_in, const int* in_sizes, int n_in,
                              void* d_out, int out_size, void* d_ws, size_t ws_size,
                              hipStream_t stream) {
  const float* x     = (const float*)d_in[0];
  const float* dlat  = (const float*)d_in[1];
  const float* sw    = (const float*)d_in[2];
  const float* sb    = (const float*)d_in[3];
  const float* wt    = (const float*)d_in[4];
  const float* bias  = (const float*)d_in[5];
  const float* nstr  = (const float*)d_in[6];
  const float* noise = (const float*)d_in[7];
  const int*   lidx  = (const int*)d_in[8];
  float* out = (float*)d_out;

  char* ws = (char*)d_ws;
  __hip_bfloat16* xsp = (__hip_bfloat16*)ws;
  __hip_bfloat16* wbT = (__hip_bfloat16*)(ws + WBT_OFF_B);
  float* sbuf = (float*)(ws + S_OFF_B);
  float* dpre = (float*)(ws + D_OFF_B);
  float* w2   = (float*)(ws + W2_OFF_B);

  hipFuncSetAttribute((const void*)conv_kernel,
                      hipFuncAttributeMaxDynamicSharedMemorySize, 147456);

  hipMemsetAsync(dpre, 0, 16 * 512 * sizeof(float), stream);
  style_kernel<<<32, 256, 0, stream>>>(dlat, sw, sb, lidx, sbuf);
  w2_kernel<<<1024, 256, 0, stream>>>(wt, w2);
  dpart_kernel<<<128, 256, 0, stream>>>(w2, sbuf, dpre);
  wbt_kernel<<<576, 256, 0, stream>>>(wt, wbT);
  xpad_kernel<<<17424, 256, 0, stream>>>(x, sbuf, xsp);
  conv_kernel<<<1024, 512, 147456, stream>>>(xsp, wbT, dpre, bias, noise, nstr, out);
}